// Round 12
// baseline (253.967 us; speedup 1.0000x reference)
//
#include <hip/hip_runtime.h>
#include <math.h>

// VectorQuantizer: argmin_k ||x_n - c_k||^2, N=32768, K=8192, D=64, fp32.
// Round-18: register-footprint cut (stripe-serial accs) + 4-wave blocks ->
// 3 blocks/CU (12 waves) instead of the 8-wave/CU ceiling of r12-r17.
//
// r17 post-mortem: bank conflicts 0 (fix verified) but NO speedup; occupancy
// stuck 21% (8 waves/CU). Unified-file accounting explains r9/r13/r16/r17:
// scheduler budget = arch VGPR + acc VGPRs. r17: 116+64=180 > 170 -> 2
// waves/SIMD -> second 8-wave block can't land. r16 (spilled to 64+64=128):
// 4 w/SIMD, 46% occupancy. With 2 w/SIMD, MFMA(99k cy) + LDS(55k) + VALU
// (50k) can't overlap -> 259k-cy wall, MfmaUtil 43%.
// Changes (same math, same LDS patterns):
//  * TPB=256: 4 waves x 64 codes = 256 codes/block (NKB=32). Blocks occupy
//    1 wave/SIMD each -> residency steps of 4 waves.
//  * Stripe-serial: MFMA+argmin stripe 0 (accs A,B = 32 regs), then reuse
//    the same acc regs for stripe 1 -> peak regs ~148 <= 170.
//  * __launch_bounds__(256,3): cap 170 (r16 lesson: cap well above the
//    estimated live set; WRITE_SIZE is the spill tripwire).
//  * LDS 34.8KB: bufX[2][16KB] (SROWS=64 subtiles) + ldsRed[4][64].
//    Splitter sr=lane, skc=w: wave-writes = two contiguous 512B windows
//    (2-way bank pairing = free; r16 verified 0 conflicts).
// Numerics identical to r15/r16/r17 (all passed, absmax 0): 2-plane f16
// split (plane1 denormal-zeroed, plane2 pre-scaled 2^12), 3 products
// (A=h1c*h1x 4-chain; B=h1c*h2x + h2c*h1x 8-chain, same order), dist =
// fmaf(-2, fmaf(B,2^-12,A), csq), per-lane argmin ascending code strict <,
// shfl_xor(32) half-merge, LDS 4-wave merge, device atomicMin(u64 fkey
// (negative-safe) <<32|code) across the 32 kb-blocks = first-occurrence.
// C/D layout (measured m74/m101): col=lane&31, row=(reg&3)+8*(reg>>2)+4*(lane>>5).

typedef __attribute__((ext_vector_type(8)))  _Float16 h8v;
typedef __attribute__((ext_vector_type(16))) float f16v;

constexpr int NROWS = 32768;
constexpr int KC    = 8192;
constexpr int DD    = 64;
constexpr int TPB   = 256;            // 4 waves, 64 codes each
constexpr int PTPB  = 256;            // pre/fin kernel block size
constexpr int NKB   = 32;             // code-block columns (256 codes each)
constexpr int RPB   = 1024;           // rows per block (32 row-blocks)
constexpr int SROWS = 64;             // rows per subtile
constexpr int NSUB  = RPB / SROWS;    // 16 bodies

__device__ __forceinline__ void split2h(float v, _Float16& h1, _Float16& h2) {
  const float av = fabsf(v);
  _Float16 a = (_Float16)v;                  // RNE
  if (av < 6.1035156e-5f) a = (_Float16)0.f; // keep plane-1 out of f16 denormals
  h1 = a;
  h2 = (_Float16)((v - (float)a) * 4096.f);  // exact residual, scaled 2^12
}

// Monotone map: unsigned order of mapped bits == float order (handles negatives).
__device__ __forceinline__ unsigned fkey(float f) {
  const unsigned u = __float_as_uint(f);
  return u ^ (((unsigned)((int)u >> 31)) | 0x80000000u);
}

// Pre-kernel (128 blocks, 4 threads/code): split cb into frag-ordered groups
// (32 codes x 4096 halves; lane h*32+l = code l, k = kc*16+h*8+j), csq, and
// init gkey. Unchanged from r15-r17 (passed).
__global__ void vq_pre_kernel(const float* __restrict__ cb,
                              _Float16* __restrict__ cbSwz,
                              float* __restrict__ csq,
                              unsigned long long* __restrict__ gkey) {
  const int gidx = blockIdx.x * PTPB + threadIdx.x;  // 0..32767
  gkey[gidx] = 0xFFFFFFFFFFFFFFFFull;                // one slot per row
  const int code = gidx >> 2;
  const int kc4  = gidx & 3;
  const float* cp = cb + (size_t)code * DD + kc4 * 16;
  float v[16];
#pragma unroll
  for (int d = 0; d < 16; d += 4) {
    const float4 g = *(const float4*)(cp + d);
    v[d] = g.x; v[d + 1] = g.y; v[d + 2] = g.z; v[d + 3] = g.w;
  }
  float s = 0.f;
#pragma unroll
  for (int d = 0; d < 16; ++d) s = fmaf(v[d], v[d], s);
  s += __shfl_xor(s, 1, 64);
  s += __shfl_xor(s, 2, 64);
  _Float16 p1[16], p2[16];
#pragma unroll
  for (int d = 0; d < 16; ++d) split2h(v[d], p1[d], p2[d]);
  const int g = code >> 5, l = code & 31;
  _Float16* base = cbSwz + (size_t)g * 4096;
#pragma unroll
  for (int p = 0; p < 2; ++p) {
    const _Float16* pl = p ? p2 : p1;
#pragma unroll
    for (int h = 0; h < 2; ++h) {
      h8v wv;
#pragma unroll
      for (int j = 0; j < 8; ++j) wv[j] = pl[h * 8 + j];
      *(h8v*)(base + (p * 4 + kc4) * 512 + (h * 32 + l) * 8) = wv;
    }
  }
  if (kc4 == 0) csq[code] = s;
}

// Split 16 raw floats (LR0..LR3) into 2 f16 planes and ds_write chunk-format.
// Thread (sr = lane, skc = w): wave-write = two contiguous 512B windows
// (rows 0-31 vs 32-63 in different chunks) -> 2-way bank pairing, free.
#define SPLITWRITE(PAR)                                                        \
  {                                                                            \
    const float ff[16] = {LR0.x, LR0.y, LR0.z, LR0.w, LR1.x, LR1.y, LR1.z,     \
                          LR1.w, LR2.x, LR2.y, LR2.z, LR2.w, LR3.x, LR3.y,     \
                          LR3.z, LR3.w};                                       \
    _Pragma("unroll")                                                          \
    for (int h = 0; h < 2; ++h) {                                              \
      h8v p1v, p2v;                                                            \
      _Pragma("unroll")                                                        \
      for (int j = 0; j < 8; ++j) {                                            \
        _Float16 a_, b_;                                                       \
        split2h(ff[h * 8 + j], a_, b_);                                        \
        p1v[j] = a_; p2v[j] = b_;                                              \
      }                                                                        \
      *(h8v*)&bufX[PAR][((sg2 * 2 + 0) * 4 + skc) * 512 + (h * 32 + sr31) * 8] = p1v; \
      *(h8v*)&bufX[PAR][((sg2 * 2 + 1) * 4 + skc) * 512 + (h * 32 + sr31) * 8] = p2v; \
    }                                                                          \
  }

__global__ __launch_bounds__(TPB, 3)
void vq_mfma_kernel(const float* __restrict__ x, const _Float16* __restrict__ cbSwz,
                    const float* __restrict__ csq_g,
                    unsigned long long* __restrict__ gkey) {
  __shared__ alignas(16) _Float16 bufX[2][8192];              // 32768 B
  __shared__ alignas(16) unsigned long long ldsRed[4][SROWS]; // 2048 B

  const int tid  = threadIdx.x;
  const int lane = tid & 63;
  const int w    = tid >> 6;
  const int half = lane >> 5;
  const int col  = lane & 31;
  const int kb   = blockIdx.x & (NKB - 1);
  const int bn   = blockIdx.x >> 5;
  const size_t nbase = (size_t)bn * RPB;

  // ---- Persistent code fragments: 2 stripes x 2 planes x 4 kc = 64 VGPR.
  h8v cbfr[2][2][4];
#pragma unroll
  for (int q = 0; q < 2; ++q)
#pragma unroll
    for (int p = 0; p < 2; ++p)
#pragma unroll
      for (int kc = 0; kc < 4; ++kc)
        cbfr[q][p][kc] = *(const h8v*)(cbSwz +
            (size_t)(kb * 8 + w * 2 + q) * 4096 + (p * 4 + kc) * 512 + lane * 8);

  // csq for this lane's 32 code-slots (one-time; 32 VGPR).
  const int cbase = kb * 256 + w * 64 + 4 * half;
  float csq[2][16];
#pragma unroll
  for (int q = 0; q < 2; ++q)
#pragma unroll
    for (int i = 0; i < 16; ++i)
      csq[q][i] = csq_g[cbase + q * 32 + (i & 3) + 8 * (i >> 2)];

  // Splitter task ids: thread covers (row sr, k-chunk skc) = 16 floats.
  const int sr = lane, skc = w;
  const int sg2 = sr >> 5, sr31 = sr & 31;

  // ---- Prologue: stage subtile 0 into buf 0.
  float4 LR0, LR1, LR2, LR3;
  {
    const float* xp = x + (nbase + sr) * DD + skc * 16;
    LR0 = ((const float4*)xp)[0]; LR1 = ((const float4*)xp)[1];
    LR2 = ((const float4*)xp)[2]; LR3 = ((const float4*)xp)[3];
    SPLITWRITE(0);
  }
  asm volatile("s_waitcnt lgkmcnt(0)\n\ts_barrier" ::: "memory");

  const f16v Z = {0.f,0.f,0.f,0.f,0.f,0.f,0.f,0.f,0.f,0.f,0.f,0.f,0.f,0.f,0.f,0.f};

#pragma unroll 1
  for (int t = 0; t < NSUB; ++t) {
    const int par = t & 1;
    // Issue raw loads for subtile t+1 (consumed at body bottom; far away).
    if (t + 1 < NSUB) {
      const float* xp = x + (nbase + (size_t)(t + 1) * SROWS + sr) * DD + skc * 16;
      LR0 = ((const float4*)xp)[0]; LR1 = ((const float4*)xp)[1];
      LR2 = ((const float4*)xp)[2]; LR3 = ((const float4*)xp)[3];
    }
    // 2 col-groups of 32 x-rows each.
#pragma unroll
    for (int cg = 0; cg < 2; ++cg) {
      h8v xfr[2][4];
#pragma unroll
      for (int p = 0; p < 2; ++p)
#pragma unroll
        for (int kc = 0; kc < 4; ++kc)
          xfr[p][kc] = *(const h8v*)&bufX[par][((cg * 2 + p) * 4 + kc) * 512 + lane * 8];

      float bd = INFINITY;
      unsigned bc = 0u;
      // ---- Stripe 0 (codes cbase..cbase+31): accs live = 32 VGPR.
      {
        __builtin_amdgcn_s_setprio(1);
        f16v A = Z, B = Z;
#pragma unroll
        for (int kc = 0; kc < 4; ++kc)
          A = __builtin_amdgcn_mfma_f32_32x32x16_f16(cbfr[0][0][kc], xfr[0][kc], A, 0, 0, 0);
#pragma unroll
        for (int kc = 0; kc < 4; ++kc)
          B = __builtin_amdgcn_mfma_f32_32x32x16_f16(cbfr[0][0][kc], xfr[1][kc], B, 0, 0, 0);
#pragma unroll
        for (int kc = 0; kc < 4; ++kc)
          B = __builtin_amdgcn_mfma_f32_32x32x16_f16(cbfr[0][1][kc], xfr[0][kc], B, 0, 0, 0);
        __builtin_amdgcn_s_setprio(0);
#pragma unroll
        for (int i = 0; i < 16; ++i) {
          const float di = fmaf(-2.f, fmaf(B[i], 2.44140625e-4f, A[i]), csq[0][i]);
          if (di < bd) { bd = di; bc = (unsigned)(cbase + (i & 3) + 8 * (i >> 2)); }
        }
      }
      // ---- Stripe 1 (codes cbase+32..+63): reuses the same acc registers.
      {
        __builtin_amdgcn_s_setprio(1);
        f16v A = Z, B = Z;
#pragma unroll
        for (int kc = 0; kc < 4; ++kc)
          A = __builtin_amdgcn_mfma_f32_32x32x16_f16(cbfr[1][0][kc], xfr[0][kc], A, 0, 0, 0);
#pragma unroll
        for (int kc = 0; kc < 4; ++kc)
          B = __builtin_amdgcn_mfma_f32_32x32x16_f16(cbfr[1][0][kc], xfr[1][kc], B, 0, 0, 0);
#pragma unroll
        for (int kc = 0; kc < 4; ++kc)
          B = __builtin_amdgcn_mfma_f32_32x32x16_f16(cbfr[1][1][kc], xfr[0][kc], B, 0, 0, 0);
        __builtin_amdgcn_s_setprio(0);
#pragma unroll
        for (int i = 0; i < 16; ++i) {
          const float di = fmaf(-2.f, fmaf(B[i], 2.44140625e-4f, A[i]), csq[1][i]);
          if (di < bd) { bd = di; bc = (unsigned)(cbase + 32 + (i & 3) + 8 * (i >> 2)); }
        }
      }
      unsigned long long key = ((unsigned long long)fkey(bd) << 32) | bc;
      const unsigned long long o = __shfl_xor(key, 32, 64);
      if (o < key) key = o;
      if (half == 0) ldsRed[w][cg * 32 + col] = key;
    }
    // Split + write subtile t+1 into the other buffer.
    if (t + 1 < NSUB) SPLITWRITE(par ^ 1);
    asm volatile("s_waitcnt lgkmcnt(0)\n\ts_barrier" ::: "memory");
    // Merge 4 waves per row; publish via device-scope u64 atomicMin.
    if (tid < SROWS) {
      unsigned long long k0 = ldsRed[0][tid];
#pragma unroll
      for (int w2 = 1; w2 < 4; ++w2) {
        const unsigned long long o2 = ldsRed[w2][tid];
        if (o2 < k0) k0 = o2;
      }
      atomicMin(&gkey[nbase + (size_t)t * SROWS + tid], k0);
    }
    asm volatile("s_barrier" ::: "memory");
  }
}

// Final pass: key -> int32 index.
__global__ void vq_fin_kernel(const unsigned long long* __restrict__ gkey,
                              int* __restrict__ out) {
  const int n = blockIdx.x * PTPB + threadIdx.x;
  out[n] = (int)(unsigned)(gkey[n] & 0xFFFFFFFFull);
}

extern "C" void kernel_launch(void* const* d_in, const int* in_sizes, int n_in,
                              void* d_out, int out_size, void* d_ws, size_t ws_size,
                              hipStream_t stream) {
  const float* x  = (const float*)d_in[0];   // [N, 64] fp32
  const float* cb = (const float*)d_in[1];   // [K, 64] fp32
  int* out = (int*)d_out;                    // [N] int32

  // ws: cbSwz 2MB | csq 32KB | gkey 256KB  (total 2.33MB)
  _Float16* cbSwz = (_Float16*)d_ws;
  float* csq_g = (float*)((char*)d_ws + (size_t)KC * DD * 2 * 2);
  unsigned long long* gkey =
      (unsigned long long*)((char*)csq_g + (size_t)KC * 4);

  vq_pre_kernel<<<dim3(KC * 4 / PTPB), dim3(PTPB), 0, stream>>>(cb, cbSwz, csq_g, gkey);
  vq_mfma_kernel<<<dim3(NKB * (NROWS / RPB)), dim3(TPB), 0, stream>>>(
      x, cbSwz, csq_g, gkey);
  vq_fin_kernel<<<dim3(NROWS / PTPB), dim3(PTPB), 0, stream>>>(gkey, out);
}

// Round 14
// 201.433 us; speedup vs baseline: 1.2608x; 1.2608x over previous
//
#include <hip/hip_runtime.h>
#include <math.h>

// VectorQuantizer: argmin_k ||x_n - c_k||^2, N=32768, K=8192, D=64, fp32.
// Round-19 RESUBMIT (previous bench failed in infra: "container failed
// twice" -- no data). r18 minus 16 VGPRs (no LR prefetch regs) -> live set
// ~158 <= 170 so __launch_bounds__(256,3) fits WITHOUT the cbfr spill.
//
// r18 post-mortem: VGPR 84 + WRITE 35.8MB + MfmaUtil 20% = allocator spilled
// cbfr to scratch (live set ~172 > 170 cap by ~2 regs). r17 evidence: unified
// reg accounting (arch+acc) 180 > 170 -> 2 waves/SIMD -> 8 waves/CU ceiling;
// r16 proved 2 blocks/CU occupancy is reachable. This round removes exactly
// the marginal registers: x is loaded directly inside SPLITWRITE (each
// subtile is read by 32 kb-blocks -> 31/32 L2 hits ~200cy, amortized over a
// ~15k cy body; 12 waves of TLP cover the rest).
// Geometry (r18, passed absmax 0): grid = 32 bn x 32 kb; block = 1024 rows
// x 256 codes; 4 waves x 64 codes; blocks occupy 1 wave/SIMD each -> 3
// blocks/CU = 12 waves at <=170 regs. LDS 34.8KB (3 blocks fit).
//  * Stripe-serial MFMA+argmin: accs A,B = 32 regs live, reused per stripe.
//  * Splitter (sr=lane, skc=w): wave-writes = two contiguous 512B windows
//    (2-way pairing = free; 0 conflicts verified r16/r17/r18).
//  * Per-lane argmin ascending code strict <, shfl_xor(32) half-merge, LDS
//    4-wave merge, device atomicMin(u64 fkey<<32|code) across kb-blocks.
// Numerics identical to r15-r18 (all passed, absmax 0): 2-plane f16 split
// (plane1 denormal-zeroed, plane2 pre-scaled 2^12), 3 products (A=h1c*h1x
// 4-chain; B=h1c*h2x + h2c*h1x 8-chain), dist = fmaf(-2, fmaf(B,2^-12,A),
// csq), fkey u64 (negative-safe), lowest-code ties = first-occurrence.
// C/D layout (measured m74/m101): col=lane&31, row=(reg&3)+8*(reg>>2)+4*(lane>>5).

typedef __attribute__((ext_vector_type(8)))  _Float16 h8v;
typedef __attribute__((ext_vector_type(16))) float f16v;

constexpr int NROWS = 32768;
constexpr int KC    = 8192;
constexpr int DD    = 64;
constexpr int TPB   = 256;            // 4 waves, 64 codes each
constexpr int PTPB  = 256;            // pre/fin kernel block size
constexpr int NKB   = 32;             // code-block columns (256 codes each)
constexpr int RPB   = 1024;           // rows per block (32 row-blocks)
constexpr int SROWS = 64;             // rows per subtile
constexpr int NSUB  = RPB / SROWS;    // 16 bodies

__device__ __forceinline__ void split2h(float v, _Float16& h1, _Float16& h2) {
  const float av = fabsf(v);
  _Float16 a = (_Float16)v;                  // RNE
  if (av < 6.1035156e-5f) a = (_Float16)0.f; // keep plane-1 out of f16 denormals
  h1 = a;
  h2 = (_Float16)((v - (float)a) * 4096.f);  // exact residual, scaled 2^12
}

// Monotone map: unsigned order of mapped bits == float order (handles negatives).
__device__ __forceinline__ unsigned fkey(float f) {
  const unsigned u = __float_as_uint(f);
  return u ^ (((unsigned)((int)u >> 31)) | 0x80000000u);
}

// Pre-kernel (128 blocks, 4 threads/code): split cb into frag-ordered groups
// (32 codes x 4096 halves; lane h*32+l = code l, k = kc*16+h*8+j), csq, and
// init gkey. Unchanged from r15-r18 (passed).
__global__ void vq_pre_kernel(const float* __restrict__ cb,
                              _Float16* __restrict__ cbSwz,
                              float* __restrict__ csq,
                              unsigned long long* __restrict__ gkey) {
  const int gidx = blockIdx.x * PTPB + threadIdx.x;  // 0..32767
  gkey[gidx] = 0xFFFFFFFFFFFFFFFFull;                // one slot per row
  const int code = gidx >> 2;
  const int kc4  = gidx & 3;
  const float* cp = cb + (size_t)code * DD + kc4 * 16;
  float v[16];
#pragma unroll
  for (int d = 0; d < 16; d += 4) {
    const float4 g = *(const float4*)(cp + d);
    v[d] = g.x; v[d + 1] = g.y; v[d + 2] = g.z; v[d + 3] = g.w;
  }
  float s = 0.f;
#pragma unroll
  for (int d = 0; d < 16; ++d) s = fmaf(v[d], v[d], s);
  s += __shfl_xor(s, 1, 64);
  s += __shfl_xor(s, 2, 64);
  _Float16 p1[16], p2[16];
#pragma unroll
  for (int d = 0; d < 16; ++d) split2h(v[d], p1[d], p2[d]);
  const int g = code >> 5, l = code & 31;
  _Float16* base = cbSwz + (size_t)g * 4096;
#pragma unroll
  for (int p = 0; p < 2; ++p) {
    const _Float16* pl = p ? p2 : p1;
#pragma unroll
    for (int h = 0; h < 2; ++h) {
      h8v wv;
#pragma unroll
      for (int j = 0; j < 8; ++j) wv[j] = pl[h * 8 + j];
      *(h8v*)(base + (p * 4 + kc4) * 512 + (h * 32 + l) * 8) = wv;
    }
  }
  if (kc4 == 0) csq[code] = s;
}

// Load 16 raw floats of subtile TT directly, split into 2 f16 planes, and
// ds_write chunk-format. No persistent prefetch registers (r19 change).
// Thread (sr = lane, skc = w): wave-write = two contiguous 512B windows.
#define SPLITWRITE(PAR, TT)                                                    \
  {                                                                            \
    const float* xp_ = x + (nbase + (size_t)(TT) * SROWS + sr) * DD + skc * 16;\
    const float4 q0_ = ((const float4*)xp_)[0];                                \
    const float4 q1_ = ((const float4*)xp_)[1];                                \
    const float4 q2_ = ((const float4*)xp_)[2];                                \
    const float4 q3_ = ((const float4*)xp_)[3];                                \
    const float ff[16] = {q0_.x, q0_.y, q0_.z, q0_.w, q1_.x, q1_.y, q1_.z,     \
                          q1_.w, q2_.x, q2_.y, q2_.z, q2_.w, q3_.x, q3_.y,     \
                          q3_.z, q3_.w};                                       \
    _Pragma("unroll")                                                          \
    for (int h = 0; h < 2; ++h) {                                              \
      h8v p1v, p2v;                                                            \
      _Pragma("unroll")                                                        \
      for (int j = 0; j < 8; ++j) {                                            \
        _Float16 a_, b_;                                                       \
        split2h(ff[h * 8 + j], a_, b_);                                        \
        p1v[j] = a_; p2v[j] = b_;                                              \
      }                                                                        \
      *(h8v*)&bufX[PAR][((sg2 * 2 + 0) * 4 + skc) * 512 + (h * 32 + sr31) * 8] = p1v; \
      *(h8v*)&bufX[PAR][((sg2 * 2 + 1) * 4 + skc) * 512 + (h * 32 + sr31) * 8] = p2v; \
    }                                                                          \
  }

__global__ __launch_bounds__(TPB, 3)
void vq_mfma_kernel(const float* __restrict__ x, const _Float16* __restrict__ cbSwz,
                    const float* __restrict__ csq_g,
                    unsigned long long* __restrict__ gkey) {
  __shared__ alignas(16) _Float16 bufX[2][8192];              // 32768 B
  __shared__ alignas(16) unsigned long long ldsRed[4][SROWS]; // 2048 B

  const int tid  = threadIdx.x;
  const int lane = tid & 63;
  const int w    = tid >> 6;
  const int half = lane >> 5;
  const int col  = lane & 31;
  const int kb   = blockIdx.x & (NKB - 1);
  const int bn   = blockIdx.x >> 5;
  const size_t nbase = (size_t)bn * RPB;

  // ---- Persistent code fragments: 2 stripes x 2 planes x 4 kc = 64 VGPR.
  h8v cbfr[2][2][4];
#pragma unroll
  for (int q = 0; q < 2; ++q)
#pragma unroll
    for (int p = 0; p < 2; ++p)
#pragma unroll
      for (int kc = 0; kc < 4; ++kc)
        cbfr[q][p][kc] = *(const h8v*)(cbSwz +
            (size_t)(kb * 8 + w * 2 + q) * 4096 + (p * 4 + kc) * 512 + lane * 8);

  // csq for this lane's 32 code-slots (one-time; 32 VGPR).
  const int cbase = kb * 256 + w * 64 + 4 * half;
  float csq[2][16];
#pragma unroll
  for (int q = 0; q < 2; ++q)
#pragma unroll
    for (int i = 0; i < 16; ++i)
      csq[q][i] = csq_g[cbase + q * 32 + (i & 3) + 8 * (i >> 2)];

  // Splitter task ids: thread covers (row sr, k-chunk skc) = 16 floats.
  const int sr = lane, skc = w;
  const int sg2 = sr >> 5, sr31 = sr & 31;

  // ---- Prologue: stage subtile 0 into buf 0.
  SPLITWRITE(0, 0);
  asm volatile("s_waitcnt lgkmcnt(0)\n\ts_barrier" ::: "memory");

  const f16v Z = {0.f,0.f,0.f,0.f,0.f,0.f,0.f,0.f,0.f,0.f,0.f,0.f,0.f,0.f,0.f,0.f};

#pragma unroll 1
  for (int t = 0; t < NSUB; ++t) {
    const int par = t & 1;
    // 2 col-groups of 32 x-rows each.
#pragma unroll
    for (int cg = 0; cg < 2; ++cg) {
      h8v xfr[2][4];
#pragma unroll
      for (int p = 0; p < 2; ++p)
#pragma unroll
        for (int kc = 0; kc < 4; ++kc)
          xfr[p][kc] = *(const h8v*)&bufX[par][((cg * 2 + p) * 4 + kc) * 512 + lane * 8];

      float bd = INFINITY;
      unsigned bc = 0u;
      // ---- Stripe 0 (codes cbase..cbase+31): accs live = 32 VGPR.
      {
        __builtin_amdgcn_s_setprio(1);
        f16v A = Z, B = Z;
#pragma unroll
        for (int kc = 0; kc < 4; ++kc)
          A = __builtin_amdgcn_mfma_f32_32x32x16_f16(cbfr[0][0][kc], xfr[0][kc], A, 0, 0, 0);
#pragma unroll
        for (int kc = 0; kc < 4; ++kc)
          B = __builtin_amdgcn_mfma_f32_32x32x16_f16(cbfr[0][0][kc], xfr[1][kc], B, 0, 0, 0);
#pragma unroll
        for (int kc = 0; kc < 4; ++kc)
          B = __builtin_amdgcn_mfma_f32_32x32x16_f16(cbfr[0][1][kc], xfr[0][kc], B, 0, 0, 0);
        __builtin_amdgcn_s_setprio(0);
#pragma unroll
        for (int i = 0; i < 16; ++i) {
          const float di = fmaf(-2.f, fmaf(B[i], 2.44140625e-4f, A[i]), csq[0][i]);
          if (di < bd) { bd = di; bc = (unsigned)(cbase + (i & 3) + 8 * (i >> 2)); }
        }
      }
      // ---- Stripe 1 (codes cbase+32..+63): reuses the same acc registers.
      {
        __builtin_amdgcn_s_setprio(1);
        f16v A = Z, B = Z;
#pragma unroll
        for (int kc = 0; kc < 4; ++kc)
          A = __builtin_amdgcn_mfma_f32_32x32x16_f16(cbfr[1][0][kc], xfr[0][kc], A, 0, 0, 0);
#pragma unroll
        for (int kc = 0; kc < 4; ++kc)
          B = __builtin_amdgcn_mfma_f32_32x32x16_f16(cbfr[1][0][kc], xfr[1][kc], B, 0, 0, 0);
#pragma unroll
        for (int kc = 0; kc < 4; ++kc)
          B = __builtin_amdgcn_mfma_f32_32x32x16_f16(cbfr[1][1][kc], xfr[0][kc], B, 0, 0, 0);
        __builtin_amdgcn_s_setprio(0);
#pragma unroll
        for (int i = 0; i < 16; ++i) {
          const float di = fmaf(-2.f, fmaf(B[i], 2.44140625e-4f, A[i]), csq[1][i]);
          if (di < bd) { bd = di; bc = (unsigned)(cbase + 32 + (i & 3) + 8 * (i >> 2)); }
        }
      }
      unsigned long long key = ((unsigned long long)fkey(bd) << 32) | bc;
      const unsigned long long o = __shfl_xor(key, 32, 64);
      if (o < key) key = o;
      if (half == 0) ldsRed[w][cg * 32 + col] = key;
    }
    // Load + split + write subtile t+1 into the other buffer.
    if (t + 1 < NSUB) SPLITWRITE(par ^ 1, t + 1);
    asm volatile("s_waitcnt lgkmcnt(0)\n\ts_barrier" ::: "memory");
    // Merge 4 waves per row; publish via device-scope u64 atomicMin.
    if (tid < SROWS) {
      unsigned long long k0 = ldsRed[0][tid];
#pragma unroll
      for (int w2 = 1; w2 < 4; ++w2) {
        const unsigned long long o2 = ldsRed[w2][tid];
        if (o2 < k0) k0 = o2;
      }
      atomicMin(&gkey[nbase + (size_t)t * SROWS + tid], k0);
    }
    asm volatile("s_barrier" ::: "memory");
  }
}

// Final pass: key -> int32 index.
__global__ void vq_fin_kernel(const unsigned long long* __restrict__ gkey,
                              int* __restrict__ out) {
  const int n = blockIdx.x * PTPB + threadIdx.x;
  out[n] = (int)(unsigned)(gkey[n] & 0xFFFFFFFFull);
}

extern "C" void kernel_launch(void* const* d_in, const int* in_sizes, int n_in,
                              void* d_out, int out_size, void* d_ws, size_t ws_size,
                              hipStream_t stream) {
  const float* x  = (const float*)d_in[0];   // [N, 64] fp32
  const float* cb = (const float*)d_in[1];   // [K, 64] fp32
  int* out = (int*)d_out;                    // [N] int32

  // ws: cbSwz 2MB | csq 32KB | gkey 256KB  (total 2.33MB)
  _Float16* cbSwz = (_Float16*)d_ws;
  float* csq_g = (float*)((char*)d_ws + (size_t)KC * DD * 2 * 2);
  unsigned long long* gkey =
      (unsigned long long*)((char*)csq_g + (size_t)KC * 4);

  vq_pre_kernel<<<dim3(KC * 4 / PTPB), dim3(PTPB), 0, stream>>>(cb, cbSwz, csq_g, gkey);
  vq_mfma_kernel<<<dim3(NKB * (NROWS / RPB)), dim3(TPB), 0, stream>>>(
      x, cbSwz, csq_g, gkey);
  vq_fin_kernel<<<dim3(NROWS / PTPB), dim3(PTPB), 0, stream>>>(gkey, out);
}

// Round 15
// 176.888 us; speedup vs baseline: 1.4357x; 1.1388x over previous
//
#include <hip/hip_runtime.h>
#include <math.h>

// VectorQuantizer: argmin_k ||x_n - c_k||^2, N=32768, K=8192, D=64, fp32.
// Round-20: FRAGMENT-DIRECT STREAMING -- zero LDS, zero barriers in main.
//
// r18/r19 post-mortem: (256,3) spills regardless of live-set trimming
// (VGPR 84 + 21-35MB scratch twice) -> occupancy-forcing abandoned.
// r17 audit: of the 16.5k cy/body/CU wall, only 6.1k is MFMA; the rest is
// x-staging (LDS write+read, split VALU) and barrier drains -- all of which
// exist only because x is split in-kernel through shared LDS. This round:
//  * Pre-kernel splits BOTH cb and x into frag-ordered global buffers
//    (cbSwz 2MB, xSwz 8MB; identical group layout: group g = 4096 halves,
//    chunk (p,kc) = 64 lanes x 8 f16, lane h*32+l = row/code l of group,
//    k = kc*16+h*8+j).
//  * Main kernel: wave holds its 64 codes' frags (64 VGPR, loaded once) +
//    csq (32 VGPR); per body loads one 32-row x-group's frags DIRECTLY
//    from global into regs (8x dwordx4, coalesced; all 4 waves read the
//    same 8KB -> L1-served; plain-load path = 25-60 B/cy/CU, NOT the
//    1.8 B/cy/wave global_load_lds wall). Then 24 MFMA (setprio), 32-slot
//    argmin, shfl_xor(32) half-merge, one wave-atomic atomicMin per body.
//    NO __shared__, NO s_barrier, NO ds ops anywhere in the main kernel.
//  * TPB=256 (1-wave/SIMD granularity), launch_bounds(256,2) (cap 256,
//    zero spill risk); natural alloc ~160 -> 3 waves/SIMD if <=170.
//  * Grid 1024 = 32 bn x 32 kb (RPB=1024, 32 bodies of 32 rows).
// Numerics identical to r15-r19 (all passed, absmax 0): 2-plane f16 split
// (plane1 denormal-zeroed, plane2 pre-scaled 2^12), 3 products (A=h1c*h1x
// 4-chain; B=h1c*h2x + h2c*h1x 8-chain), dist = fmaf(-2, fmaf(B,2^-12,A),
// csq), per-lane argmin ascending code strict <, fkey u64 (negative-safe),
// atomicMin order-independent exact, lowest-code ties = first-occurrence.
// C/D layout (measured m74/m101): col=lane&31, row=(reg&3)+8*(reg>>2)+4*(lane>>5).

typedef __attribute__((ext_vector_type(8)))  _Float16 h8v;
typedef __attribute__((ext_vector_type(16))) float f16v;

constexpr int NROWS = 32768;
constexpr int KC    = 8192;
constexpr int DD    = 64;
constexpr int TPB   = 256;            // 4 waves, 64 codes each
constexpr int PTPB  = 256;            // pre/fin kernel block size
constexpr int NKB   = 32;             // code-block columns (256 codes each)
constexpr int RPB   = 1024;           // rows per block -> 32 bn
constexpr int NBODY = RPB / 32;       // 32 bodies (one 32-row group each)
constexpr int CBBLK = KC * 4 / PTPB;  // 128 cb-split blocks in pre-kernel

__device__ __forceinline__ void split2h(float v, _Float16& h1, _Float16& h2) {
  const float av = fabsf(v);
  _Float16 a = (_Float16)v;                  // RNE
  if (av < 6.1035156e-5f) a = (_Float16)0.f; // keep plane-1 out of f16 denormals
  h1 = a;
  h2 = (_Float16)((v - (float)a) * 4096.f);  // exact residual, scaled 2^12
}

// Monotone map: unsigned order of mapped bits == float order (handles negatives).
__device__ __forceinline__ unsigned fkey(float f) {
  const unsigned u = __float_as_uint(f);
  return u ^ (((unsigned)((int)u >> 31)) | 0x80000000u);
}

// Pre-kernel (640 blocks, 4 threads/row): blocks [0,128) split cb -> cbSwz
// (+csq, +gkey init); blocks [128,640) split x -> xSwz. Same frag-order
// writer as r15-r19 (passed) for both.
__global__ void vq_pre_kernel(const float* __restrict__ cb,
                              const float* __restrict__ x,
                              _Float16* __restrict__ cbSwz,
                              _Float16* __restrict__ xSwz,
                              float* __restrict__ csq,
                              unsigned long long* __restrict__ gkey) {
  const int bid = blockIdx.x, tid = threadIdx.x;
  const bool isCb = (bid < CBBLK);
  const int gidx = (isCb ? bid : bid - CBBLK) * PTPB + tid;
  const int row = gidx >> 2;
  const int kc4 = gidx & 3;
  const float* cp = (isCb ? cb : x) + (size_t)row * DD + kc4 * 16;
  float v[16];
#pragma unroll
  for (int d = 0; d < 16; d += 4) {
    const float4 g = *(const float4*)(cp + d);
    v[d] = g.x; v[d + 1] = g.y; v[d + 2] = g.z; v[d + 3] = g.w;
  }
  if (isCb) {
    gkey[gidx] = 0xFFFFFFFFFFFFFFFFull;   // gidx 0..32767 covers all rows
    float s = 0.f;
#pragma unroll
    for (int d = 0; d < 16; ++d) s = fmaf(v[d], v[d], s);
    s += __shfl_xor(s, 1, 64);
    s += __shfl_xor(s, 2, 64);
    if (kc4 == 0) csq[row] = s;
  }
  _Float16 p1[16], p2[16];
#pragma unroll
  for (int d = 0; d < 16; ++d) split2h(v[d], p1[d], p2[d]);
  const int g = row >> 5, l = row & 31;
  _Float16* base = (isCb ? cbSwz : xSwz) + (size_t)g * 4096;
#pragma unroll
  for (int p = 0; p < 2; ++p) {
    const _Float16* pl = p ? p2 : p1;
#pragma unroll
    for (int h = 0; h < 2; ++h) {
      h8v wv;
#pragma unroll
      for (int j = 0; j < 8; ++j) wv[j] = pl[h * 8 + j];
      *(h8v*)(base + (p * 4 + kc4) * 512 + (h * 32 + l) * 8) = wv;
    }
  }
}

__global__ __launch_bounds__(TPB, 2)
void vq_mfma_kernel(const _Float16* __restrict__ cbSwz,
                    const _Float16* __restrict__ xSwz,
                    const float* __restrict__ csq_g,
                    unsigned long long* __restrict__ gkey) {
  const int tid  = threadIdx.x;
  const int lane = tid & 63;
  const int w    = tid >> 6;
  const int half = lane >> 5;
  const int col  = lane & 31;
  const int kb   = blockIdx.x & (NKB - 1);
  const int bn   = blockIdx.x >> 5;

  // ---- Persistent code fragments: 2 stripes x 2 planes x 4 kc = 64 VGPR.
  h8v cbfr[2][2][4];
#pragma unroll
  for (int q = 0; q < 2; ++q)
#pragma unroll
    for (int p = 0; p < 2; ++p)
#pragma unroll
      for (int kc = 0; kc < 4; ++kc)
        cbfr[q][p][kc] = *(const h8v*)(cbSwz +
            (size_t)(kb * 8 + w * 2 + q) * 4096 + (p * 4 + kc) * 512 + lane * 8);

  // csq for this lane's 32 code-slots (one-time; 32 VGPR).
  const int cbase = kb * 256 + w * 64 + 4 * half;
  float csq[2][16];
#pragma unroll
  for (int q = 0; q < 2; ++q)
#pragma unroll
    for (int i = 0; i < 16; ++i)
      csq[q][i] = csq_g[cbase + q * 32 + (i & 3) + 8 * (i >> 2)];

  const f16v Z = {0.f,0.f,0.f,0.f,0.f,0.f,0.f,0.f,0.f,0.f,0.f,0.f,0.f,0.f,0.f,0.f};

  // ---- Barrier-free, LDS-free main loop over 32-row x-groups.
#pragma unroll 2
  for (int t = 0; t < NBODY; ++t) {
    const size_t rg = (size_t)bn * NBODY + t;
    // x fragments straight from global (frag-ordered; all 4 waves read the
    // same 8KB -> L1; coalesced 1KB per instruction).
    const _Float16* xg = xSwz + rg * 4096 + lane * 8;
    h8v xfr[2][4];
#pragma unroll
    for (int p = 0; p < 2; ++p)
#pragma unroll
      for (int kc = 0; kc < 4; ++kc)
        xfr[p][kc] = *(const h8v*)(xg + (p * 4 + kc) * 512);

    float bd = INFINITY;
    unsigned bc = 0u;
    // ---- Stripe 0 (codes cbase..+31): A=h1c*h1x, B=h1c*h2x + h2c*h1x.
    {
      __builtin_amdgcn_s_setprio(1);
      f16v A = Z, B = Z;
#pragma unroll
      for (int kc = 0; kc < 4; ++kc)
        A = __builtin_amdgcn_mfma_f32_32x32x16_f16(cbfr[0][0][kc], xfr[0][kc], A, 0, 0, 0);
#pragma unroll
      for (int kc = 0; kc < 4; ++kc)
        B = __builtin_amdgcn_mfma_f32_32x32x16_f16(cbfr[0][0][kc], xfr[1][kc], B, 0, 0, 0);
#pragma unroll
      for (int kc = 0; kc < 4; ++kc)
        B = __builtin_amdgcn_mfma_f32_32x32x16_f16(cbfr[0][1][kc], xfr[0][kc], B, 0, 0, 0);
      __builtin_amdgcn_s_setprio(0);
#pragma unroll
      for (int i = 0; i < 16; ++i) {
        const float di = fmaf(-2.f, fmaf(B[i], 2.44140625e-4f, A[i]), csq[0][i]);
        if (di < bd) { bd = di; bc = (unsigned)(cbase + (i & 3) + 8 * (i >> 2)); }
      }
    }
    // ---- Stripe 1 (codes cbase+32..+63): reuses the same acc registers.
    {
      __builtin_amdgcn_s_setprio(1);
      f16v A = Z, B = Z;
#pragma unroll
      for (int kc = 0; kc < 4; ++kc)
        A = __builtin_amdgcn_mfma_f32_32x32x16_f16(cbfr[1][0][kc], xfr[0][kc], A, 0, 0, 0);
#pragma unroll
      for (int kc = 0; kc < 4; ++kc)
        B = __builtin_amdgcn_mfma_f32_32x32x16_f16(cbfr[1][0][kc], xfr[1][kc], B, 0, 0, 0);
#pragma unroll
      for (int kc = 0; kc < 4; ++kc)
        B = __builtin_amdgcn_mfma_f32_32x32x16_f16(cbfr[1][1][kc], xfr[0][kc], B, 0, 0, 0);
      __builtin_amdgcn_s_setprio(0);
#pragma unroll
      for (int i = 0; i < 16; ++i) {
        const float di = fmaf(-2.f, fmaf(B[i], 2.44140625e-4f, A[i]), csq[1][i]);
        if (di < bd) { bd = di; bc = (unsigned)(cbase + 32 + (i & 3) + 8 * (i >> 2)); }
      }
    }
    // Merge the two lane-halves (they hold complementary code sets for the
    // same x-row = col), then publish: one predicated wave-atomic per body.
    unsigned long long key = ((unsigned long long)fkey(bd) << 32) | bc;
    const unsigned long long o = __shfl_xor(key, 32, 64);
    if (o < key) key = o;
    if (half == 0) atomicMin(&gkey[rg * 32 + col], key);
  }
}

// Final pass: key -> int32 index.
__global__ void vq_fin_kernel(const unsigned long long* __restrict__ gkey,
                              int* __restrict__ out) {
  const int n = blockIdx.x * PTPB + threadIdx.x;
  out[n] = (int)(unsigned)(gkey[n] & 0xFFFFFFFFull);
}

extern "C" void kernel_launch(void* const* d_in, const int* in_sizes, int n_in,
                              void* d_out, int out_size, void* d_ws, size_t ws_size,
                              hipStream_t stream) {
  const float* x  = (const float*)d_in[0];   // [N, 64] fp32
  const float* cb = (const float*)d_in[1];   // [K, 64] fp32
  int* out = (int*)d_out;                    // [N] int32

  // ws: cbSwz 2MB | xSwz 8MB | csq 32KB | gkey 256KB  (total ~10.3MB)
  _Float16* cbSwz = (_Float16*)d_ws;
  _Float16* xSwz  = cbSwz + (size_t)KC * DD * 2;
  float* csq_g = (float*)(xSwz + (size_t)NROWS * DD * 2);
  unsigned long long* gkey =
      (unsigned long long*)((char*)csq_g + (size_t)KC * 4);

  vq_pre_kernel<<<dim3(CBBLK + NROWS * 4 / PTPB), dim3(PTPB), 0, stream>>>(
      cb, x, cbSwz, xSwz, csq_g, gkey);
  vq_mfma_kernel<<<dim3(NKB * (NROWS / RPB)), dim3(TPB), 0, stream>>>(
      cbSwz, xSwz, csq_g, gkey);
  vq_fin_kernel<<<dim3(NROWS / PTPB), dim3(PTPB), 0, stream>>>(gkey, out);
}